// Round 2
// baseline (307.371 us; speedup 1.0000x reference)
//
#include <hip/hip_runtime.h>
#include <math.h>

#define NCLS   1000
#define NV4    250                 // float4 per row
#define NROWS  16384
#define NBLOCKS 2048               // 8 blocks/CU -> 32 waves/CU resident
#define ROWS_PER_BLOCK (NROWS / NBLOCKS)   // 8
#define INV_TEMP 0.5f
#define NEG_INF (-INFINITY)

// merge two ordered top-2 pairs: (a1>=a2) U (b1>=b2) -> (a1,a2)
__device__ __forceinline__ void merge2(float& a1, float& a2, float b1, float b2) {
    const float mn = fminf(a1, b1);
    a1 = fmaxf(a1, b1);
    a2 = fmaxf(mn, fmaxf(a2, b2));
}

__device__ __forceinline__ void top2_of4(const float4 v, float& t1, float& t2) {
    const float hi1 = fmaxf(v.x, v.y), lo1 = fminf(v.x, v.y);
    const float hi2 = fmaxf(v.z, v.w), lo2 = fminf(v.z, v.w);
    t1 = fmaxf(hi1, hi2);
    t2 = fmaxf(fminf(hi1, hi2), fmaxf(lo1, lo2));
}

// Persistent blocks: block b handles rows b, b+2048, ... (8 rows).
// Whole block (256 thr) covers one row of all 5 matrices per iteration:
// thread t owns float4 #t of the row (t<250). 2-row register pipeline:
// next row's 20 dwordx4 + target are in flight during the current reduce.
// Double-buffered micro-LDS, ONE barrier per row. Thread 0 finishes:
// 4-wave merge, margins, softmax, output write, running block max.
__global__ __launch_bounds__(256) void fused_persistent(
    const float* __restrict__ o1, const float* __restrict__ o2,
    const float* __restrict__ o3, const float* __restrict__ o4,
    const float* __restrict__ mim, const int* __restrict__ targets,
    float* __restrict__ out, float* __restrict__ blockmax)
{
    const int tid  = threadIdx.x;
    const int lane = tid & 63;
    const int wid  = tid >> 6;
    const bool act = (tid < NV4);
    const int  li  = act ? tid : (NV4 - 1);      // inactive lanes dup-load

    const float4* mats[5] = {
        (const float4*)o1, (const float4*)o2, (const float4*)o3,
        (const float4*)o4, (const float4*)mim };

    __shared__ float lds[2][4][5][2];   // [buf][wave][mat][{m1,m2}]
    __shared__ float ltv[2][5];         // [buf][mat] target value

    // prefetch row 0 of this block's stride
    int r = blockIdx.x;
    float4 nxt[5];
    #pragma unroll
    for (int m = 0; m < 5; ++m) nxt[m] = mats[m][(size_t)r * NV4 + li];
    int tnxt = targets[r];

    float bmax = NEG_INF;               // meaningful on thread 0 only

    #pragma unroll
    for (int it = 0; it < ROWS_PER_BLOCK; ++it) {
        // rotate pipeline: cur <- nxt, issue next row's loads immediately
        float4 cur[5];
        #pragma unroll
        for (int m = 0; m < 5; ++m) cur[m] = nxt[m];
        const int tcur = tnxt;
        const int rn = r + NBLOCKS;
        if (it + 1 < ROWS_PER_BLOCK) {
            #pragma unroll
            for (int m = 0; m < 5; ++m) nxt[m] = mats[m][(size_t)rn * NV4 + li];
            tnxt = targets[rn];
        }

        const int buf = it & 1;

        // target value: owning thread drops it in LDS (tcur < 1000 -> owner < 250)
        if (act && tid == (tcur >> 2)) {
            const int comp = tcur & 3;
            #pragma unroll
            for (int m = 0; m < 5; ++m) {
                const float4 v = cur[m];
                ltv[buf][m] = (comp == 0) ? v.x : (comp == 1) ? v.y
                            : (comp == 2) ? v.z : v.w;
            }
        }

        // per-matrix: thread-local top2 -> 6-step wave butterfly -> LDS
        #pragma unroll
        for (int m = 0; m < 5; ++m) {
            float t1, t2;
            if (act) top2_of4(cur[m], t1, t2);
            else     { t1 = NEG_INF; t2 = NEG_INF; }
            #pragma unroll
            for (int off = 32; off >= 1; off >>= 1) {
                const float q1 = __shfl_xor(t1, off, 64);
                const float q2 = __shfl_xor(t2, off, 64);
                merge2(t1, t2, q1, q2);
            }
            if (lane == 0) { lds[buf][wid][m][0] = t1; lds[buf][wid][m][1] = t2; }
        }

        __syncthreads();   // single barrier per row (LDS double-buffered:
                           // next write to this buf is 2 barriers away)

        if (tid == 0) {
            float g[5];
            float rmax = NEG_INF;
            #pragma unroll
            for (int m = 0; m < 5; ++m) {
                float m1 = lds[buf][0][m][0], m2 = lds[buf][0][m][1];
                merge2(m1, m2, lds[buf][1][m][0], lds[buf][1][m][1]);
                merge2(m1, m2, lds[buf][2][m][0], lds[buf][2][m][1]);
                merge2(m1, m2, lds[buf][3][m][0], lds[buf][3][m][1]);
                g[m] = (m1 == ltv[buf][m]) ? (m1 - m2) : 0.0f;
                if (m < 4) rmax = fmaxf(rmax, m1);
            }
            bmax = fmaxf(bmax, rmax);

            const float q0 = g[0] * INV_TEMP, q1 = g[1] * INV_TEMP,
                        q2 = g[2] * INV_TEMP, q3 = g[3] * INV_TEMP,
                        q4 = g[4] * INV_TEMP;
            const float pm = fmaxf(fmaxf(fmaxf(q0, q1), fmaxf(q2, q3)), q4);
            const float x0 = expf(q0 - pm), x1 = expf(q1 - pm),
                        x2 = expf(q2 - pm), x3 = expf(q3 - pm),
                        x4 = expf(q4 - pm);
            const float inv = 1.0f / (x0 + x1 + x2 + x3 + x4);
            float* b = out + 1 + (size_t)r * 5;
            b[0] = x0 * inv; b[1] = x1 * inv; b[2] = x2 * inv;
            b[3] = x3 * inv; b[4] = x4 * inv;
        }

        r = rn;
    }

    if (tid == 0) blockmax[blockIdx.x] = bmax;
}

// Single block reduces blockmax[2048] -> out[0].
__global__ __launch_bounds__(1024) void final_max_kernel(
    const float* __restrict__ blockmax, float* __restrict__ out)
{
    const float4* w4 = (const float4*)blockmax;
    float m = NEG_INF;
    if (threadIdx.x < NBLOCKS / 4) {     // 512 threads, one float4 each
        const float4 v = w4[threadIdx.x];
        m = fmaxf(fmaxf(v.x, v.y), fmaxf(v.z, v.w));
    }
    #pragma unroll
    for (int off = 32; off >= 1; off >>= 1)
        m = fmaxf(m, __shfl_xor(m, off, 64));
    __shared__ float s[16];
    const int lane = threadIdx.x & 63, wid = threadIdx.x >> 6;
    if (lane == 0) s[wid] = m;
    __syncthreads();
    if (threadIdx.x == 0) {
        float mm = s[0];
        #pragma unroll
        for (int i = 1; i < 16; ++i) mm = fmaxf(mm, s[i]);
        out[0] = mm;
    }
}

extern "C" void kernel_launch(void* const* d_in, const int* in_sizes, int n_in,
                              void* d_out, int out_size, void* d_ws, size_t ws_size,
                              hipStream_t stream) {
    const float* o1  = (const float*)d_in[0];
    const float* o2  = (const float*)d_in[1];
    const float* o3  = (const float*)d_in[2];
    const float* o4  = (const float*)d_in[3];
    const float* mim = (const float*)d_in[4];
    const int*   tgt = (const int*)d_in[5];

    float* out = (float*)d_out;
    float* blockmax = (float*)d_ws;                  // NBLOCKS floats

    fused_persistent<<<NBLOCKS, 256, 0, stream>>>(o1, o2, o3, o4, mim, tgt,
                                                  out, blockmax);
    final_max_kernel<<<1, 1024, 0, stream>>>(blockmax, out);
}

// Round 3
// 291.392 us; speedup vs baseline: 1.0548x; 1.0548x over previous
//
#include <hip/hip_runtime.h>
#include <math.h>

#define NCLS  1000
#define NROWS 16384
#define INV_TEMP 0.5f
#define NEG_INF (-INFINITY)

// merge two ordered top-2 pairs: (a1>=a2) U (b1>=b2) -> (a1,a2)
__device__ __forceinline__ void merge2(float& a1, float& a2, float b1, float b2) {
    const float mn = fminf(a1, b1);
    a1 = fmaxf(a1, b1);
    a2 = fmaxf(mn, fmaxf(a2, b2));
}

// thread-local top-2 of 4 float4 (16 values)
__device__ __forceinline__ void top2_16(const float4 v0, const float4 v1,
                                        const float4 v2, const float4 v3,
                                        float& m1, float& m2)
{
    float t1[4], t2[4];
    const float4 vv[4] = {v0, v1, v2, v3};
    #pragma unroll
    for (int i = 0; i < 4; ++i) {
        const float hi1 = fmaxf(vv[i].x, vv[i].y), lo1 = fminf(vv[i].x, vv[i].y);
        const float hi2 = fmaxf(vv[i].z, vv[i].w), lo2 = fminf(vv[i].z, vv[i].w);
        t1[i] = fmaxf(hi1, hi2);
        t2[i] = fmaxf(fminf(hi1, hi2), fmaxf(lo1, lo2));
    }
    merge2(t1[0], t2[0], t1[1], t2[1]);
    merge2(t1[2], t2[2], t1[3], t2[3]);
    merge2(t1[0], t2[0], t1[2], t2[2]);
    m1 = t1[0]; m2 = t2[0];
}

// pick component of the target's float4 (owner lane holds it; others garbage-ok)
__device__ __forceinline__ float pick(const float4 v0, const float4 v1,
                                      const float4 v2, const float4 v3,
                                      int chunk, int comp)
{
    const float4 sel = (chunk == 0) ? v0 : (chunk == 1) ? v1
                     : (chunk == 2) ? v2 : v3;
    return (comp == 0) ? sel.x : (comp == 1) ? sel.y
         : (comp == 2) ? sel.z : sel.w;
}

// One wave per row, all 5 matrices. De-serialized vs round 1:
//  - targets[row] issued FIRST (round 1 issued it last; the tv-broadcast
//    bpermute address depends on it -> forced vmcnt(0) before any compute)
//  - thread-local top2s consume each matrix as its 4 loads land
//  - ONE butterfly loop interleaving all 5 matrices: 10 independent
//    shuffles per step (round 1: 5 serial 6-step chains)
// No LDS, no barriers.
__global__ __launch_bounds__(256) void fused_margin_softmax(
    const float* __restrict__ o1, const float* __restrict__ o2,
    const float* __restrict__ o3, const float* __restrict__ o4,
    const float* __restrict__ mim, const int* __restrict__ targets,
    float* __restrict__ out, float* __restrict__ wavemax)
{
    const int lane = threadIdx.x & 63;
    const int row  = blockIdx.x * 4 + (threadIdx.x >> 6);   // wave-uniform

    const int tgt = targets[row];            // FIRST load issued
    const int q     = tgt >> 2;              // owning float4 index in row
    const int comp  = tgt & 3;
    const int chunk = q >> 6;                // which of the 4 per-lane chunks
    const int src   = q & 63;                // owning lane (always < 58 in chunk 3)

    const int i3 = (lane < 58) ? (192 + lane) : 249;
    const float4* pa = (const float4*)(o1  + (size_t)row * NCLS);
    const float4* pb = (const float4*)(o2  + (size_t)row * NCLS);
    const float4* pc = (const float4*)(o3  + (size_t)row * NCLS);
    const float4* pd = (const float4*)(o4  + (size_t)row * NCLS);
    const float4* pe = (const float4*)(mim + (size_t)row * NCLS);

    float4 a0 = pa[lane], a1 = pa[64 + lane], a2 = pa[128 + lane], a3 = pa[i3];
    float4 b0 = pb[lane], b1 = pb[64 + lane], b2 = pb[128 + lane], b3 = pb[i3];
    float4 c0 = pc[lane], c1 = pc[64 + lane], c2 = pc[128 + lane], c3 = pc[i3];
    float4 d0 = pd[lane], d1 = pd[64 + lane], d2 = pd[128 + lane], d3 = pd[i3];
    float4 e0 = pe[lane], e1 = pe[64 + lane], e2 = pe[128 + lane], e3 = pe[i3];

    // target-value candidates (pre-tail-mask: owner lane is never masked)
    float tvc[5];
    tvc[0] = pick(a0, a1, a2, a3, chunk, comp);
    tvc[1] = pick(b0, b1, b2, b3, chunk, comp);
    tvc[2] = pick(c0, c1, c2, c3, chunk, comp);
    tvc[3] = pick(d0, d1, d2, d3, chunk, comp);
    tvc[4] = pick(e0, e1, e2, e3, chunk, comp);

    if (lane >= 58) {
        const float4 n4 = make_float4(NEG_INF, NEG_INF, NEG_INF, NEG_INF);
        a3 = n4; b3 = n4; c3 = n4; d3 = n4; e3 = n4;
    }

    // thread-local top2 per matrix (each consumes its regs as loads land)
    float t1[5], t2[5];
    top2_16(a0, a1, a2, a3, t1[0], t2[0]);
    top2_16(b0, b1, b2, b3, t1[1], t2[1]);
    top2_16(c0, c1, c2, c3, t1[2], t2[2]);
    top2_16(d0, d1, d2, d3, t1[3], t2[3]);
    top2_16(e0, e1, e2, e3, t1[4], t2[4]);

    // broadcast the 5 target values (independent shuffles, address ready early)
    float tv[5];
    #pragma unroll
    for (int m = 0; m < 5; ++m) tv[m] = __shfl(tvc[m], src, 64);

    // single interleaved butterfly: 6 steps x 10 independent shuffles
    #pragma unroll
    for (int off = 32; off >= 1; off >>= 1) {
        float q1[5], q2[5];
        #pragma unroll
        for (int m = 0; m < 5; ++m) {
            q1[m] = __shfl_xor(t1[m], off, 64);
            q2[m] = __shfl_xor(t2[m], off, 64);
        }
        #pragma unroll
        for (int m = 0; m < 5; ++m) merge2(t1[m], t2[m], q1[m], q2[m]);
    }

    // margins + row max (mats 0..3)
    float g[5];
    #pragma unroll
    for (int m = 0; m < 5; ++m)
        g[m] = (t1[m] == tv[m]) ? (t1[m] - t2[m]) : 0.0f;
    const float rowmax = fmaxf(fmaxf(t1[0], t1[1]), fmaxf(t1[2], t1[3]));

    // fused softmax (wave-uniform)
    const float p0 = g[0] * INV_TEMP, p1 = g[1] * INV_TEMP, p2 = g[2] * INV_TEMP,
                p3 = g[3] * INV_TEMP, p4 = g[4] * INV_TEMP;
    const float pm = fmaxf(fmaxf(fmaxf(p0, p1), fmaxf(p2, p3)), p4);
    const float x0 = expf(p0 - pm), x1 = expf(p1 - pm), x2 = expf(p2 - pm),
                x3 = expf(p3 - pm), x4 = expf(p4 - pm);
    const float inv = 1.0f / (x0 + x1 + x2 + x3 + x4);

    if (lane < 5) {
        const float r = (lane == 0) ? x0 : (lane == 1) ? x1 : (lane == 2) ? x2
                      : (lane == 3) ? x3 : x4;
        out[1 + (size_t)row * 5 + lane] = r * inv;
    }
    if (lane == 5) wavemax[row] = rowmax;
}

// Single block of 1024 threads reduces wavemax[16384] -> out[0].
__global__ __launch_bounds__(1024) void final_max_kernel(
    const float* __restrict__ wavemax, float* __restrict__ out)
{
    const float4* w4 = (const float4*)wavemax;
    float m = NEG_INF;
    #pragma unroll
    for (int i = 0; i < (NROWS / 4) / 1024; ++i) {
        const float4 v = w4[threadIdx.x + i * 1024];
        m = fmaxf(fmaxf(fmaxf(m, v.x), v.y), fmaxf(v.z, v.w));
    }
    #pragma unroll
    for (int off = 32; off >= 1; off >>= 1)
        m = fmaxf(m, __shfl_xor(m, off, 64));
    __shared__ float s[16];
    const int lane = threadIdx.x & 63, wid = threadIdx.x >> 6;
    if (lane == 0) s[wid] = m;
    __syncthreads();
    if (threadIdx.x == 0) {
        float mm = s[0];
        #pragma unroll
        for (int i = 1; i < 16; ++i) mm = fmaxf(mm, s[i]);
        out[0] = mm;
    }
}

extern "C" void kernel_launch(void* const* d_in, const int* in_sizes, int n_in,
                              void* d_out, int out_size, void* d_ws, size_t ws_size,
                              hipStream_t stream) {
    const float* o1  = (const float*)d_in[0];
    const float* o2  = (const float*)d_in[1];
    const float* o3  = (const float*)d_in[2];
    const float* o4  = (const float*)d_in[3];
    const float* mim = (const float*)d_in[4];
    const int*   tgt = (const int*)d_in[5];

    float* out = (float*)d_out;
    float* wavemax = (float*)d_ws;                   // NROWS floats (64 KB)

    fused_margin_softmax<<<NROWS / 4, 256, 0, stream>>>(o1, o2, o3, o4, mim, tgt,
                                                        out, wavemax);
    final_max_kernel<<<1, 1024, 0, stream>>>(wavemax, out);
}

// Round 4
// 264.280 us; speedup vs baseline: 1.1631x; 1.1026x over previous
//
#include <hip/hip_runtime.h>
#include <math.h>

#define NCLS  1000
#define NROWS 16384
#define INV_TEMP 0.5f
#define NEG_INF (-INFINITY)

// ext_vector float4 so __builtin_nontemporal_load applies cleanly
typedef float vf4 __attribute__((ext_vector_type(4)));

__device__ __forceinline__ vf4 ldnt(const vf4* p) {
    return __builtin_nontemporal_load(p);
}

// merge two ordered top-2 pairs: (a1>=a2) U (b1>=b2) -> (a1,a2)
__device__ __forceinline__ void merge2(float& a1, float& a2, float b1, float b2) {
    const float mn = fminf(a1, b1);
    a1 = fmaxf(a1, b1);
    a2 = fmaxf(mn, fmaxf(a2, b2));
}

// thread-local top-2 of 4 vf4 (16 values)
__device__ __forceinline__ void top2_16(const vf4 v0, const vf4 v1,
                                        const vf4 v2, const vf4 v3,
                                        float& m1, float& m2)
{
    float t1[4], t2[4];
    const vf4 vv[4] = {v0, v1, v2, v3};
    #pragma unroll
    for (int i = 0; i < 4; ++i) {
        const float hi1 = fmaxf(vv[i].x, vv[i].y), lo1 = fminf(vv[i].x, vv[i].y);
        const float hi2 = fmaxf(vv[i].z, vv[i].w), lo2 = fminf(vv[i].z, vv[i].w);
        t1[i] = fmaxf(hi1, hi2);
        t2[i] = fmaxf(fminf(hi1, hi2), fmaxf(lo1, lo2));
    }
    merge2(t1[0], t2[0], t1[1], t2[1]);
    merge2(t1[2], t2[2], t1[3], t2[3]);
    merge2(t1[0], t2[0], t1[2], t2[2]);
    m1 = t1[0]; m2 = t2[0];
}

// pick component of the target's float4 (owner lane holds it; others garbage-ok)
__device__ __forceinline__ float pick(const vf4 v0, const vf4 v1,
                                      const vf4 v2, const vf4 v3,
                                      int chunk, int comp)
{
    const vf4 sel = (chunk == 0) ? v0 : (chunk == 1) ? v1
                  : (chunk == 2) ? v2 : v3;
    return (comp == 0) ? sel.x : (comp == 1) ? sel.y
         : (comp == 2) ? sel.z : sel.w;
}

// Round-3 structure (one wave per row, all 5 matrices, fused softmax) with
// ALL 20 row loads non-temporal: the 328 MB/iter stream never allocates in
// L2/L3. Single-variable probe of the memory-path ceiling theory.
__global__ __launch_bounds__(256) void fused_margin_softmax(
    const float* __restrict__ o1, const float* __restrict__ o2,
    const float* __restrict__ o3, const float* __restrict__ o4,
    const float* __restrict__ mim, const int* __restrict__ targets,
    float* __restrict__ out, float* __restrict__ wavemax)
{
    const int lane = threadIdx.x & 63;
    const int row  = blockIdx.x * 4 + (threadIdx.x >> 6);   // wave-uniform

    const int tgt = targets[row];            // first load issued; cached
    const int q     = tgt >> 2;
    const int comp  = tgt & 3;
    const int chunk = q >> 6;
    const int src   = q & 63;                // owning lane (always < 58 in chunk 3)

    const int i3 = (lane < 58) ? (192 + lane) : 249;
    const vf4* pa = (const vf4*)(o1  + (size_t)row * NCLS);
    const vf4* pb = (const vf4*)(o2  + (size_t)row * NCLS);
    const vf4* pc = (const vf4*)(o3  + (size_t)row * NCLS);
    const vf4* pd = (const vf4*)(o4  + (size_t)row * NCLS);
    const vf4* pe = (const vf4*)(mim + (size_t)row * NCLS);

    vf4 a0 = ldnt(pa + lane), a1 = ldnt(pa + 64 + lane),
        a2 = ldnt(pa + 128 + lane), a3 = ldnt(pa + i3);
    vf4 b0 = ldnt(pb + lane), b1 = ldnt(pb + 64 + lane),
        b2 = ldnt(pb + 128 + lane), b3 = ldnt(pb + i3);
    vf4 c0 = ldnt(pc + lane), c1 = ldnt(pc + 64 + lane),
        c2 = ldnt(pc + 128 + lane), c3 = ldnt(pc + i3);
    vf4 d0 = ldnt(pd + lane), d1 = ldnt(pd + 64 + lane),
        d2 = ldnt(pd + 128 + lane), d3 = ldnt(pd + i3);
    vf4 e0 = ldnt(pe + lane), e1 = ldnt(pe + 64 + lane),
        e2 = ldnt(pe + 128 + lane), e3 = ldnt(pe + i3);

    // target-value candidates (pre-tail-mask: owner lane is never masked)
    float tvc[5];
    tvc[0] = pick(a0, a1, a2, a3, chunk, comp);
    tvc[1] = pick(b0, b1, b2, b3, chunk, comp);
    tvc[2] = pick(c0, c1, c2, c3, chunk, comp);
    tvc[3] = pick(d0, d1, d2, d3, chunk, comp);
    tvc[4] = pick(e0, e1, e2, e3, chunk, comp);

    if (lane >= 58) {
        const vf4 n4 = {NEG_INF, NEG_INF, NEG_INF, NEG_INF};
        a3 = n4; b3 = n4; c3 = n4; d3 = n4; e3 = n4;
    }

    // thread-local top2 per matrix
    float t1[5], t2[5];
    top2_16(a0, a1, a2, a3, t1[0], t2[0]);
    top2_16(b0, b1, b2, b3, t1[1], t2[1]);
    top2_16(c0, c1, c2, c3, t1[2], t2[2]);
    top2_16(d0, d1, d2, d3, t1[3], t2[3]);
    top2_16(e0, e1, e2, e3, t1[4], t2[4]);

    // broadcast the 5 target values
    float tv[5];
    #pragma unroll
    for (int m = 0; m < 5; ++m) tv[m] = __shfl(tvc[m], src, 64);

    // single interleaved butterfly: 6 steps x 10 independent shuffles
    #pragma unroll
    for (int off = 32; off >= 1; off >>= 1) {
        float q1[5], q2[5];
        #pragma unroll
        for (int m = 0; m < 5; ++m) {
            q1[m] = __shfl_xor(t1[m], off, 64);
            q2[m] = __shfl_xor(t2[m], off, 64);
        }
        #pragma unroll
        for (int m = 0; m < 5; ++m) merge2(t1[m], t2[m], q1[m], q2[m]);
    }

    // margins + row max (mats 0..3)
    float g[5];
    #pragma unroll
    for (int m = 0; m < 5; ++m)
        g[m] = (t1[m] == tv[m]) ? (t1[m] - t2[m]) : 0.0f;
    const float rowmax = fmaxf(fmaxf(t1[0], t1[1]), fmaxf(t1[2], t1[3]));

    // fused softmax (wave-uniform)
    const float p0 = g[0] * INV_TEMP, p1 = g[1] * INV_TEMP, p2 = g[2] * INV_TEMP,
                p3 = g[3] * INV_TEMP, p4 = g[4] * INV_TEMP;
    const float pm = fmaxf(fmaxf(fmaxf(p0, p1), fmaxf(p2, p3)), p4);
    const float x0 = expf(p0 - pm), x1 = expf(p1 - pm), x2 = expf(p2 - pm),
                x3 = expf(p3 - pm), x4 = expf(p4 - pm);
    const float inv = 1.0f / (x0 + x1 + x2 + x3 + x4);

    if (lane < 5) {
        const float r = (lane == 0) ? x0 : (lane == 1) ? x1 : (lane == 2) ? x2
                      : (lane == 3) ? x3 : x4;
        out[1 + (size_t)row * 5 + lane] = r * inv;
    }
    if (lane == 5) wavemax[row] = rowmax;
}

// Single block of 1024 threads reduces wavemax[16384] -> out[0].
__global__ __launch_bounds__(1024) void final_max_kernel(
    const float* __restrict__ wavemax, float* __restrict__ out)
{
    const float4* w4 = (const float4*)wavemax;
    float m = NEG_INF;
    #pragma unroll
    for (int i = 0; i < (NROWS / 4) / 1024; ++i) {
        const float4 v = w4[threadIdx.x + i * 1024];
        m = fmaxf(fmaxf(fmaxf(m, v.x), v.y), fmaxf(v.z, v.w));
    }
    #pragma unroll
    for (int off = 32; off >= 1; off >>= 1)
        m = fmaxf(m, __shfl_xor(m, off, 64));
    __shared__ float s[16];
    const int lane = threadIdx.x & 63, wid = threadIdx.x >> 6;
    if (lane == 0) s[wid] = m;
    __syncthreads();
    if (threadIdx.x == 0) {
        float mm = s[0];
        #pragma unroll
        for (int i = 1; i < 16; ++i) mm = fmaxf(mm, s[i]);
        out[0] = mm;
    }
}

extern "C" void kernel_launch(void* const* d_in, const int* in_sizes, int n_in,
                              void* d_out, int out_size, void* d_ws, size_t ws_size,
                              hipStream_t stream) {
    const float* o1  = (const float*)d_in[0];
    const float* o2  = (const float*)d_in[1];
    const float* o3  = (const float*)d_in[2];
    const float* o4  = (const float*)d_in[3];
    const float* mim = (const float*)d_in[4];
    const int*   tgt = (const int*)d_in[5];

    float* out = (float*)d_out;
    float* wavemax = (float*)d_ws;                   // NROWS floats (64 KB)

    fused_margin_softmax<<<NROWS / 4, 256, 0, stream>>>(o1, o2, o3, o4, mim, tgt,
                                                        out, wavemax);
    final_max_kernel<<<1, 1024, 0, stream>>>(wavemax, out);
}